// Round 1
// baseline (190.130 us; speedup 1.0000x reference)
//
#include <hip/hip_runtime.h>

// SwapV2: Gaussian-weighted separable soft gather.
// out[b,c,i,j] = ( sum_u sum_v wy[u]*wx[v]*X[b,c,u,v] ) / (sum(wy)*sum(wx)+1e-8)
// wy/wx depend only on (b,i,j) -> per block (one (b,i) row, 64 pixels) compute
// weights once, then a fused LDS GEMM over channels:
//   m[v,p] = sum_u Xs[u][v] * WY[u][p]        (K-loop GEMM, 4x4 reg tiles)
//   out[p] = sum_v m[v,p] * WX[v][p] / Z[p]   (short contraction + LDS reduce)

#define HH 64
#define WW 64
#define CC 32
#define PAD 68   // LDS row stride in floats: breaks stride-64 conflicts, keeps 16B align

__global__ __launch_bounds__(256, 2)
void swap_kernel(const float* __restrict__ inp,
                 const float* __restrict__ exPx,
                 const float* __restrict__ exPy,
                 const float* __restrict__ sigmax,
                 const float* __restrict__ sigmay,
                 float* __restrict__ out)
{
    __shared__ float Xs [HH * PAD];    // Xs[u][v]   : input channel tile
    __shared__ float WYs[HH * PAD];    // WYs[u][p]  : row weights per pixel
    __shared__ float WXs[WW * PAD];    // WXs[v][p]  : col weights per pixel
    __shared__ float RED[16 * PAD];    // reduction buffer [tv][p]
    __shared__ float INVZ[64];
    __shared__ float SUMY[4 * 64];
    __shared__ float SUMX[4 * 64];

    const int t  = threadIdx.x;
    const int bi = blockIdx.x;         // b*64 + i
    const int b  = bi >> 6;
    const int i  = bi & 63;

    // ---------------- phase 0: per-pixel Gaussian weights ----------------
    {
        const int p = t & 63;          // pixel j in this row
        const int g = t >> 6;          // coordinate group 0..3 (16 coords each)
        const int pixBase = bi * 64 + p;       // index into [B,H,W] params
        const float ey  = exPy[pixBase];
        const float ex  = exPx[pixBase];
        const float isy = 1.0f / sigmay[pixBase];
        const float isx = 1.0f / sigmax[pixBase];
        float sy = 0.0f, sx = 0.0f;
        #pragma unroll
        for (int k = 0; k < 16; ++k) {
            const int u = g * 16 + k;
            const float dy = ((float)u - ey) * isy;
            const float wy = __expf(-0.5f * dy * dy);
            WYs[u * PAD + p] = wy;
            sy += wy;
            const float dx = ((float)u - ex) * isx;
            const float wx = __expf(-0.5f * dx * dx);
            WXs[u * PAD + p] = wx;
            sx += wx;
        }
        SUMY[g * 64 + p] = sy;
        SUMX[g * 64 + p] = sx;
    }
    __syncthreads();
    if (t < 64) {
        const float sy = SUMY[t] + SUMY[64 + t] + SUMY[128 + t] + SUMY[192 + t];
        const float sx = SUMX[t] + SUMX[64 + t] + SUMX[128 + t] + SUMX[192 + t];
        INVZ[t] = 1.0f / (sy * sx + 1e-8f);
    }

    // ---------------- fused per-channel GEMM ----------------
    const int tp = t & 15;             // pixel-tile index  (p = tp*4 + j)
    const int tv = t >> 4;             // v-tile index      (v = tv*4 + k)
    const float* xbase = inp + (size_t)b * (CC * HH * WW);
    float*       obase = out + (size_t)b * (CC * HH * WW) + i * WW;

    for (int c = 0; c < CC; ++c) {
        __syncthreads();   // protect Xs (and RED reads of prev iter)

        // stage X[b,c] -> LDS (16 KB), coalesced float4
        {
            const float4* src = (const float4*)(xbase + c * (HH * WW));
            #pragma unroll
            for (int r = 0; r < 4; ++r) {
                const int f  = t + 256 * r;     // float4 index 0..1023
                const int u  = f >> 4;
                const int v4 = f & 15;
                const float4 d = src[f];
                *(float4*)&Xs[u * PAD + v4 * 4] = d;
            }
        }
        __syncthreads();

        // m[v,p] = sum_u Xs[u][v] * WYs[u][p] ; thread owns 4 v x 4 p
        float macc[4][4];
        #pragma unroll
        for (int k = 0; k < 4; ++k)
            #pragma unroll
            for (int j = 0; j < 4; ++j) macc[k][j] = 0.0f;

        #pragma unroll 16
        for (int u = 0; u < HH; ++u) {
            const float4 xr = *(const float4*)&Xs [u * PAD + tv * 4];
            const float4 wr = *(const float4*)&WYs[u * PAD + tp * 4];
            macc[0][0] += xr.x * wr.x;  macc[0][1] += xr.x * wr.y;
            macc[0][2] += xr.x * wr.z;  macc[0][3] += xr.x * wr.w;
            macc[1][0] += xr.y * wr.x;  macc[1][1] += xr.y * wr.y;
            macc[1][2] += xr.y * wr.z;  macc[1][3] += xr.y * wr.w;
            macc[2][0] += xr.z * wr.x;  macc[2][1] += xr.z * wr.y;
            macc[2][2] += xr.z * wr.z;  macc[2][3] += xr.z * wr.w;
            macc[3][0] += xr.w * wr.x;  macc[3][1] += xr.w * wr.y;
            macc[3][2] += xr.w * wr.z;  macc[3][3] += xr.w * wr.w;
        }

        // stage B: multiply by wx and partially reduce over this thread's 4 v
        float pb0 = 0.0f, pb1 = 0.0f, pb2 = 0.0f, pb3 = 0.0f;
        #pragma unroll
        for (int k = 0; k < 4; ++k) {
            const float4 wxr = *(const float4*)&WXs[(tv * 4 + k) * PAD + tp * 4];
            pb0 += macc[k][0] * wxr.x;
            pb1 += macc[k][1] * wxr.y;
            pb2 += macc[k][2] * wxr.z;
            pb3 += macc[k][3] * wxr.w;
        }
        *(float4*)&RED[tv * PAD + tp * 4] = make_float4(pb0, pb1, pb2, pb3);
        __syncthreads();

        // final reduce over 16 v-groups, normalize, write 64 coalesced floats
        if (t < 64) {
            float o = 0.0f;
            #pragma unroll
            for (int k = 0; k < 16; ++k) o += RED[k * PAD + t];
            obase[c * (HH * WW) + t] = o * INVZ[t];
        }
    }
}

extern "C" void kernel_launch(void* const* d_in, const int* in_sizes, int n_in,
                              void* d_out, int out_size, void* d_ws, size_t ws_size,
                              hipStream_t stream) {
    const float* inp    = (const float*)d_in[0];
    const float* exPx   = (const float*)d_in[1];
    const float* exPy   = (const float*)d_in[2];
    const float* sigmax = (const float*)d_in[3];
    const float* sigmay = (const float*)d_in[4];
    float* out = (float*)d_out;

    dim3 grid(8 * 64);   // one block per (b, i) output row
    dim3 block(256);
    hipLaunchKernelGGL(swap_kernel, grid, block, 0, stream,
                       inp, exPx, exPy, sigmax, sigmay, out);
}

// Round 2
// 109.427 us; speedup vs baseline: 1.7375x; 1.7375x over previous
//
#include <hip/hip_runtime.h>

// SwapV2: Gaussian-weighted separable soft gather, MFMA version.
//   t'[u][p] = sum_v X[u][v] * wx[v][p]     (bf16 MFMA, 3-term hi/lo split)
//   out[p]   = sum_u wy[u][p] * t'[u][p] * invZ[p]   (fp32 VALU stage-2)
// Pass 1 pre-splits X into bf16 hi/lo planes in d_ws (kills per-block convert
// redundancy). Main kernel: block = (b, i, c-half), wave w owns u-tile mt=w,
// A-frags straight from global (L2), wx B-frags + wy*invZ hoisted in VGPRs,
// cross-wave u-reduce via double-buffered LDS RED, 1 barrier per 4 channels.

#define BB 8
#define CC 32
#define HH 64
#define WW 64

typedef __attribute__((ext_vector_type(8))) short short8;   // 8 bf16 (4 VGPRs)
typedef __attribute__((ext_vector_type(4))) float f32x4;    // 4 fp32 acc
typedef unsigned int uint;

__device__ __forceinline__ uint rn_bf16(float f) {
    uint u = __float_as_uint(f);
    return (u + 0x7FFFu + ((u >> 16) & 1u)) >> 16;   // round-to-nearest-even
}
__device__ __forceinline__ float bf16_to_f(uint h) { return __uint_as_float(h << 16); }

// ---------------- pass 1: fp32 -> bf16 hi/lo planes in d_ws ----------------
__global__ void preconvert_kernel(const float* __restrict__ x,
                                  uint* __restrict__ hi, uint* __restrict__ lo)
{
    const int n = BB * CC * HH * WW / 2;     // uint (bf16-pair) count per plane
    int idx = blockIdx.x * blockDim.x + threadIdx.x;
    for (; idx < n; idx += gridDim.x * blockDim.x) {
        float2 d = ((const float2*)x)[idx];
        uint h0 = rn_bf16(d.x), h1 = rn_bf16(d.y);
        float l0 = d.x - bf16_to_f(h0), l1 = d.y - bf16_to_f(h1);
        hi[idx] = h0 | (h1 << 16);
        lo[idx] = rn_bf16(l0) | (rn_bf16(l1) << 16);
    }
}

// ---------------- LDS layout (bytes) ----------------
#define WYS_OFF   0        // WYs[u][65] fp32        : 64*65*4  = 16640
#define WXH_OFF   16640    // WXh[p][72] bf16        : 64*144   = 9216
#define WXL_OFF   25856    // WXl[p][72] bf16        : 9216  -> end 35072
#define RED_OFF   35072    // RED[2][4ch][256] fp32  : 8192  (SUMY/SUMX overlay)
#define INVZ_OFF  43264    // INVZ[64] fp32          : 256
#define LDS_BYTES 43520

__global__ __launch_bounds__(256, 3)
void swap_mfma_kernel(const float* __restrict__ exPx, const float* __restrict__ exPy,
                      const float* __restrict__ sigmax, const float* __restrict__ sigmay,
                      const uint* __restrict__ xhi, const uint* __restrict__ xlo,
                      float* __restrict__ out)
{
    __shared__ __align__(16) char lds[LDS_BYTES];
    const int t    = threadIdx.x;
    const int lane = t & 63;
    const int w    = t >> 6;          // wave id == u-tile mt
    const int q    = (t >> 4) & 3;    // quad within wave
    const int ln   = t & 15;
    const int bid   = blockIdx.x;     // (b*64 + i)*2 + chalf
    const int chalf = bid & 1;
    const int bi    = bid >> 1;
    const int b = bi >> 6, i = bi & 63;

    float* WYS = (float*)(lds + WYS_OFF);

    // -------- phase 0: per-pixel weights (wy fp32; wx bf16 hi/lo, B-layout) --------
    {
        const int p = lane;           // pixel j of this row
        const int g = w;              // coord group (16 coords)
        const int pixBase = bi * 64 + p;
        const float ey = exPy[pixBase], ex = exPx[pixBase];
        const float isy = 1.0f / sigmay[pixBase], isx = 1.0f / sigmax[pixBase];
        float sy = 0.0f, sx = 0.0f;
        #pragma unroll
        for (int k = 0; k < 16; ++k) {
            const int u = g * 16 + k;
            const float dy = ((float)u - ey) * isy;
            const float wy = __expf(-0.5f * dy * dy);
            WYS[u * 65 + p] = wy;
            sy += wy;
        }
        uint* WXH = (uint*)(lds + WXH_OFF);
        uint* WXL = (uint*)(lds + WXL_OFF);
        #pragma unroll
        for (int j = 0; j < 8; ++j) {
            const int v0 = g * 16 + 2 * j;
            const float dx0 = ((float)v0       - ex) * isx;
            const float dx1 = ((float)(v0 + 1) - ex) * isx;
            const float wx0 = __expf(-0.5f * dx0 * dx0);
            const float wx1 = __expf(-0.5f * dx1 * dx1);
            sx += wx0 + wx1;
            const uint h0 = rn_bf16(wx0), h1 = rn_bf16(wx1);
            const float l0 = wx0 - bf16_to_f(h0), l1 = wx1 - bf16_to_f(h1);
            WXH[p * 36 + g * 8 + j] = h0 | (h1 << 16);
            WXL[p * 36 + g * 8 + j] = rn_bf16(l0) | (rn_bf16(l1) << 16);
        }
        float* SUMY = (float*)(lds + RED_OFF);   // transient overlay in RED
        float* SUMX = SUMY + 256;
        SUMY[g * 64 + p] = sy;
        SUMX[g * 64 + p] = sx;
    }
    __syncthreads();
    float* INVZ = (float*)(lds + INVZ_OFF);
    if (t < 64) {
        float* SUMY = (float*)(lds + RED_OFF);
        float* SUMX = SUMY + 256;
        const float sy = SUMY[t] + SUMY[64 + t] + SUMY[128 + t] + SUMY[192 + t];
        const float sx = SUMX[t] + SUMX[64 + t] + SUMX[128 + t] + SUMX[192 + t];
        INVZ[t] = 1.0f / (sy * sx + 1e-8f);
    }
    __syncthreads();

    // -------- hoist channel-invariant fragments into registers --------
    // B-frag (wx): lane holds B[k=q*8+j][n=ln] for tile (nt, ks)
    short8 bh[4][2], bl[4][2];
    #pragma unroll
    for (int nt = 0; nt < 4; ++nt)
        #pragma unroll
        for (int ks = 0; ks < 2; ++ks) {
            const int off = (nt * 16 + ln) * 144 + ks * 64 + q * 16;
            bh[nt][ks] = *(const short8*)(lds + WXH_OFF + off);
            bl[nt][ks] = *(const short8*)(lds + WXL_OFF + off);
        }
    // wy * invZ: lane needs wy[u = w*16+q*4+r][p = nt*16+ln]
    float wyz[4][4];
    #pragma unroll
    for (int nt = 0; nt < 4; ++nt) {
        const float iz = INVZ[nt * 16 + ln];
        #pragma unroll
        for (int r = 0; r < 4; ++r)
            wyz[nt][r] = WYS[(w * 16 + q * 4 + r) * 65 + nt * 16 + ln] * iz;
    }
    __syncthreads();   // phase-0 LDS regions now dead; RED reusable

    // -------- channel loop: 16 channels, groups of 4, 1 barrier per group --------
    const int cbase = b * CC + chalf * 16;           // absolute (b,c) plane index
    float* RED = (float*)(lds + RED_OFF);
    const int rowoff = (w * 16 + ln) * 8;            // short8 offset of lane's u-row

    for (int g4 = 0; g4 < 4; ++g4) {
        float* REDb = RED + (g4 & 1) * 1024;
        #pragma unroll
        for (int k = 0; k < 4; ++k) {
            const int c = g4 * 4 + k;
            const short8* PH = ((const short8*)xhi) + (size_t)(cbase + c) * 512 + rowoff;
            const short8* PL = ((const short8*)xlo) + (size_t)(cbase + c) * 512 + rowoff;
            const short8 ah0 = PH[q],     al0 = PL[q];       // ks=0
            const short8 ah1 = PH[4 + q], al1 = PL[4 + q];   // ks=1

            f32x4 acc[4];
            #pragma unroll
            for (int nt = 0; nt < 4; ++nt) acc[nt] = (f32x4){0.f, 0.f, 0.f, 0.f};
            #pragma unroll
            for (int nt = 0; nt < 4; ++nt) {
                acc[nt] = __builtin_amdgcn_mfma_f32_16x16x32_bf16(ah0, bh[nt][0], acc[nt], 0, 0, 0);
                acc[nt] = __builtin_amdgcn_mfma_f32_16x16x32_bf16(al0, bh[nt][0], acc[nt], 0, 0, 0);
                acc[nt] = __builtin_amdgcn_mfma_f32_16x16x32_bf16(ah0, bl[nt][0], acc[nt], 0, 0, 0);
                acc[nt] = __builtin_amdgcn_mfma_f32_16x16x32_bf16(ah1, bh[nt][1], acc[nt], 0, 0, 0);
                acc[nt] = __builtin_amdgcn_mfma_f32_16x16x32_bf16(al1, bh[nt][1], acc[nt], 0, 0, 0);
                acc[nt] = __builtin_amdgcn_mfma_f32_16x16x32_bf16(ah1, bl[nt][1], acc[nt], 0, 0, 0);
            }
            // stage-2: contract u within wave's tile, then across quads
            #pragma unroll
            for (int nt = 0; nt < 4; ++nt) {
                float ps = acc[nt][0] * wyz[nt][0] + acc[nt][1] * wyz[nt][1]
                         + acc[nt][2] * wyz[nt][2] + acc[nt][3] * wyz[nt][3];
                ps += __shfl_xor(ps, 16, 64);
                ps += __shfl_xor(ps, 32, 64);
                if (q == 0) REDb[k * 256 + w * 64 + nt * 16 + ln] = ps;
            }
        }
        __syncthreads();
        // cross-wave reduce + store: 256 threads, one output each, coalesced per 64
        {
            const int kk = t >> 6, p = t & 63;
            const int c = g4 * 4 + kk;
            const float* Rk = REDb + kk * 256;
            const float o = Rk[p] + Rk[64 + p] + Rk[128 + p] + Rk[192 + p];
            out[(size_t)(cbase + c) * (HH * WW) + i * 64 + p] = o;
        }
    }
}

// ---------------- fallback (round-1 proven fp32 kernel) ----------------
#define PAD 68
__global__ __launch_bounds__(256, 2)
void swap_fallback_kernel(const float* __restrict__ inp,
                          const float* __restrict__ exPx, const float* __restrict__ exPy,
                          const float* __restrict__ sigmax, const float* __restrict__ sigmay,
                          float* __restrict__ out)
{
    __shared__ float Xs[HH * PAD];
    __shared__ float WYs[HH * PAD];
    __shared__ float WXs[WW * PAD];
    __shared__ float REDs[16 * PAD];
    __shared__ float INVZs[64];
    __shared__ float SUMYs[4 * 64];
    __shared__ float SUMXs[4 * 64];

    const int t = threadIdx.x;
    const int bi = blockIdx.x;
    const int b = bi >> 6, i = bi & 63;
    {
        const int p = t & 63, g = t >> 6;
        const int pixBase = bi * 64 + p;
        const float ey = exPy[pixBase], ex = exPx[pixBase];
        const float isy = 1.0f / sigmay[pixBase], isx = 1.0f / sigmax[pixBase];
        float sy = 0.0f, sx = 0.0f;
        #pragma unroll
        for (int k = 0; k < 16; ++k) {
            const int u = g * 16 + k;
            const float dy = ((float)u - ey) * isy;
            const float wy = __expf(-0.5f * dy * dy);
            WYs[u * PAD + p] = wy; sy += wy;
            const float dx = ((float)u - ex) * isx;
            const float wx = __expf(-0.5f * dx * dx);
            WXs[u * PAD + p] = wx; sx += wx;
        }
        SUMYs[g * 64 + p] = sy; SUMXs[g * 64 + p] = sx;
    }
    __syncthreads();
    if (t < 64) {
        const float sy = SUMYs[t] + SUMYs[64 + t] + SUMYs[128 + t] + SUMYs[192 + t];
        const float sx = SUMXs[t] + SUMXs[64 + t] + SUMXs[128 + t] + SUMXs[192 + t];
        INVZs[t] = 1.0f / (sy * sx + 1e-8f);
    }
    const int tp = t & 15, tv = t >> 4;
    const float* xbase = inp + (size_t)b * (CC * HH * WW);
    float* obase = out + (size_t)b * (CC * HH * WW) + i * WW;
    for (int c = 0; c < CC; ++c) {
        __syncthreads();
        {
            const float4* src = (const float4*)(xbase + c * (HH * WW));
            #pragma unroll
            for (int r = 0; r < 4; ++r) {
                const int f = t + 256 * r;
                const float4 d = src[f];
                *(float4*)&Xs[(f >> 4) * PAD + (f & 15) * 4] = d;
            }
        }
        __syncthreads();
        float macc[4][4];
        #pragma unroll
        for (int k = 0; k < 4; ++k)
            #pragma unroll
            for (int j = 0; j < 4; ++j) macc[k][j] = 0.0f;
        #pragma unroll 16
        for (int u = 0; u < HH; ++u) {
            const float4 xr = *(const float4*)&Xs[u * PAD + tv * 4];
            const float4 wr = *(const float4*)&WYs[u * PAD + tp * 4];
            macc[0][0] += xr.x * wr.x; macc[0][1] += xr.x * wr.y; macc[0][2] += xr.x * wr.z; macc[0][3] += xr.x * wr.w;
            macc[1][0] += xr.y * wr.x; macc[1][1] += xr.y * wr.y; macc[1][2] += xr.y * wr.z; macc[1][3] += xr.y * wr.w;
            macc[2][0] += xr.z * wr.x; macc[2][1] += xr.z * wr.y; macc[2][2] += xr.z * wr.z; macc[2][3] += xr.z * wr.w;
            macc[3][0] += xr.w * wr.x; macc[3][1] += xr.w * wr.y; macc[3][2] += xr.w * wr.z; macc[3][3] += xr.w * wr.w;
        }
        float pb0 = 0.f, pb1 = 0.f, pb2 = 0.f, pb3 = 0.f;
        #pragma unroll
        for (int k = 0; k < 4; ++k) {
            const float4 wxr = *(const float4*)&WXs[(tv * 4 + k) * PAD + tp * 4];
            pb0 += macc[k][0] * wxr.x; pb1 += macc[k][1] * wxr.y;
            pb2 += macc[k][2] * wxr.z; pb3 += macc[k][3] * wxr.w;
        }
        *(float4*)&REDs[tv * PAD + tp * 4] = make_float4(pb0, pb1, pb2, pb3);
        __syncthreads();
        if (t < 64) {
            float o = 0.0f;
            #pragma unroll
            for (int k = 0; k < 16; ++k) o += REDs[k * PAD + t];
            obase[c * (HH * WW) + t] = o * INVZs[t];
        }
    }
}

extern "C" void kernel_launch(void* const* d_in, const int* in_sizes, int n_in,
                              void* d_out, int out_size, void* d_ws, size_t ws_size,
                              hipStream_t stream) {
    const float* inp    = (const float*)d_in[0];
    const float* exPx   = (const float*)d_in[1];
    const float* exPy   = (const float*)d_in[2];
    const float* sigmax = (const float*)d_in[3];
    const float* sigmay = (const float*)d_in[4];
    float* out = (float*)d_out;

    const size_t plane_bytes = (size_t)BB * CC * HH * WW * 2;   // 8 MB per bf16 plane
    if (ws_size >= 2 * plane_bytes) {
        uint* xhi = (uint*)d_ws;
        uint* xlo = (uint*)((char*)d_ws + plane_bytes);
        hipLaunchKernelGGL(preconvert_kernel, dim3(2048), dim3(256), 0, stream,
                           inp, xhi, xlo);
        hipLaunchKernelGGL(swap_mfma_kernel, dim3(BB * HH * 2), dim3(256), 0, stream,
                           exPx, exPy, sigmax, sigmay, xhi, xlo, out);
    } else {
        hipLaunchKernelGGL(swap_fallback_kernel, dim3(BB * HH), dim3(256), 0, stream,
                           inp, exPx, exPy, sigmax, sigmay, out);
    }
}

// Round 3
// 94.567 us; speedup vs baseline: 2.0105x; 1.1571x over previous
//
#include <hip/hip_runtime.h>

// SwapV2: Gaussian-weighted separable soft gather — fused single-kernel MFMA.
//   t'[u][p] = sum_v X[u][v] * wx[v][p]     (bf16 MFMA, A=X trunc hi/lo split,
//                                            B=wx single RNE bf16 -> 4 MFMA/tile)
//   out[p]   = sum_u wy[u][p] * t'[u][p] * invZ[p]   (fp32 VALU stage-2)
// Block = (b, i, c-half), 256 thr, wave w owns u-tile mt=w. X is read as fp32
// straight from global (L2/L3-resident) and split in-register — no preconvert
// kernel. LDS: phase-0 weight regions are dead after the register hoist, so the
// main-loop RED buffer overlays WYS -> 27.5 KB -> 4 blocks/CU -> the whole
// 1024-block grid is co-resident (zero tail).

#define BB 8
#define CC 32
#define HH 64
#define WW 64

typedef __attribute__((ext_vector_type(8))) short short8;   // 8 bf16 (4 VGPRs)
typedef __attribute__((ext_vector_type(4))) float f32x4;    // 4 fp32 acc
typedef unsigned int uint;

__device__ __forceinline__ uint rn_bf16(float f) {
    uint u = __float_as_uint(f);
    return (u + 0x7FFFu + ((u >> 16) & 1u)) >> 16;   // round-to-nearest-even
}
__device__ __forceinline__ float bf16_to_f(uint h) { return __uint_as_float(h << 16); }

// truncation split of two fp32 into packed bf16 hi + packed bf16 lo.
// hi = top 16 bits (trunc); lo = x - hi exactly representable, then trunc.
// residual <= 2^-16 |x| — compensated product needs only A-side split.
__device__ __forceinline__ void split_pair(float f0, float f1, uint& hi, uint& lo) {
    const uint u0 = __float_as_uint(f0), u1 = __float_as_uint(f1);
    hi = (u0 >> 16) | (u1 & 0xFFFF0000u);
    const float l0 = f0 - __uint_as_float(u0 & 0xFFFF0000u);
    const float l1 = f1 - __uint_as_float(u1 & 0xFFFF0000u);
    lo = (__float_as_uint(l0) >> 16) | (__float_as_uint(l1) & 0xFFFF0000u);
}

// ---------------- LDS layout (bytes) ----------------
#define WYS_OFF   0        // WYs[u][65] fp32   : 64*65*4 = 16640  (dead after hoist)
#define WXH_OFF   16640    // WXh[p][72] bf16   : 64*144  = 9216   (dead after hoist)
#define SUM_OFF   25856    // SUMY[256]+SUMX[256] fp32 : 2048     (phase 0 only)
#define INVZ_OFF  27904    // INVZ[64] fp32     : 256
#define LDS_BYTES 28160
#define RED_OFF   0        // RED[2][4ch][256] fp32 : 8192 — overlays WYS (dead)

__global__ __launch_bounds__(256, 4)
void swap_fused_kernel(const float* __restrict__ inp,
                       const float* __restrict__ exPx, const float* __restrict__ exPy,
                       const float* __restrict__ sigmax, const float* __restrict__ sigmay,
                       float* __restrict__ out)
{
    __shared__ __align__(16) char lds[LDS_BYTES];
    const int t    = threadIdx.x;
    const int lane = t & 63;
    const int w    = t >> 6;          // wave id == u-tile mt
    const int q    = (t >> 4) & 3;    // quad within wave
    const int ln   = t & 15;
    const int bid   = blockIdx.x;     // (b*64 + i)*2 + chalf
    const int chalf = bid & 1;
    const int bi    = bid >> 1;
    const int b = bi >> 6, i = bi & 63;

    float* WYS = (float*)(lds + WYS_OFF);

    // -------- phase 0: per-pixel weights (wy fp32; wx RNE bf16, B-layout) --------
    {
        const int p = lane;           // pixel j of this row
        const int g = w;              // coord group (16 coords)
        const int pixBase = bi * 64 + p;
        const float ey = exPy[pixBase], ex = exPx[pixBase];
        const float isy = 1.0f / sigmay[pixBase], isx = 1.0f / sigmax[pixBase];
        float sy = 0.0f, sx = 0.0f;
        #pragma unroll
        for (int k = 0; k < 16; ++k) {
            const int u = g * 16 + k;
            const float dy = ((float)u - ey) * isy;
            const float wy = __expf(-0.5f * dy * dy);
            WYS[u * 65 + p] = wy;
            sy += wy;
        }
        uint* WXH = (uint*)(lds + WXH_OFF);
        #pragma unroll
        for (int j = 0; j < 8; ++j) {
            const int v0 = g * 16 + 2 * j;
            const float dx0 = ((float)v0       - ex) * isx;
            const float dx1 = ((float)(v0 + 1) - ex) * isx;
            const float wx0 = __expf(-0.5f * dx0 * dx0);
            const float wx1 = __expf(-0.5f * dx1 * dx1);
            sx += wx0 + wx1;
            WXH[p * 36 + g * 8 + j] = rn_bf16(wx0) | (rn_bf16(wx1) << 16);
        }
        float* SUMY = (float*)(lds + SUM_OFF);
        float* SUMX = SUMY + 256;
        SUMY[g * 64 + p] = sy;
        SUMX[g * 64 + p] = sx;
    }
    __syncthreads();
    float* INVZ = (float*)(lds + INVZ_OFF);
    if (t < 64) {
        float* SUMY = (float*)(lds + SUM_OFF);
        float* SUMX = SUMY + 256;
        const float sy = SUMY[t] + SUMY[64 + t] + SUMY[128 + t] + SUMY[192 + t];
        const float sx = SUMX[t] + SUMX[64 + t] + SUMX[128 + t] + SUMX[192 + t];
        INVZ[t] = 1.0f / (sy * sx + 1e-8f);
    }
    __syncthreads();

    // -------- hoist channel-invariant fragments into registers --------
    // B-frag (wx): lane holds B[k = ks*32 + q*8 + j][n = nt*16 + ln]
    short8 bh[4][2];
    #pragma unroll
    for (int nt = 0; nt < 4; ++nt)
        #pragma unroll
        for (int ks = 0; ks < 2; ++ks)
            bh[nt][ks] = *(const short8*)(lds + WXH_OFF + (nt * 16 + ln) * 144 + ks * 64 + q * 16);
    // wy * invZ: lane needs wy[u = w*16 + q*4 + r][p = nt*16 + ln]
    float wyz[4][4];
    #pragma unroll
    for (int nt = 0; nt < 4; ++nt) {
        const float iz = INVZ[nt * 16 + ln];
        #pragma unroll
        for (int r = 0; r < 4; ++r)
            wyz[nt][r] = WYS[(w * 16 + q * 4 + r) * 65 + nt * 16 + ln] * iz;
    }
    __syncthreads();   // phase-0 LDS now dead; RED (overlaying WYS) becomes live

    // -------- channel loop: 16 channels, groups of 4, 1 barrier per group --------
    const int cbase = b * CC + chalf * 16;           // absolute (b,c) plane index
    float* RED = (float*)(lds + RED_OFF);
    // lane's A-row: u = w*16 + ln, k-offset v = ks*32 + q*8 + j
    const float* xrow = inp + (size_t)cbase * 4096 + (w * 16 + ln) * 64 + q * 8;

    for (int g4 = 0; g4 < 4; ++g4) {
        float* REDb = RED + (g4 & 1) * 1024;
        #pragma unroll
        for (int k = 0; k < 4; ++k) {
            const int c = g4 * 4 + k;
            const float4* src = (const float4*)(xrow + (size_t)c * 4096);
            const float4 x0 = src[0];   // v = q*8 + 0..3
            const float4 x1 = src[1];   // v = q*8 + 4..7
            const float4 x2 = src[8];   // v = 32 + q*8 + 0..3
            const float4 x3 = src[9];   // v = 32 + q*8 + 4..7

            union { uint u[4]; short8 s; } Ah0, Al0, Ah1, Al1;
            split_pair(x0.x, x0.y, Ah0.u[0], Al0.u[0]);
            split_pair(x0.z, x0.w, Ah0.u[1], Al0.u[1]);
            split_pair(x1.x, x1.y, Ah0.u[2], Al0.u[2]);
            split_pair(x1.z, x1.w, Ah0.u[3], Al0.u[3]);
            split_pair(x2.x, x2.y, Ah1.u[0], Al1.u[0]);
            split_pair(x2.z, x2.w, Ah1.u[1], Al1.u[1]);
            split_pair(x3.x, x3.y, Ah1.u[2], Al1.u[2]);
            split_pair(x3.z, x3.w, Ah1.u[3], Al1.u[3]);

            f32x4 acc[4];
            #pragma unroll
            for (int nt = 0; nt < 4; ++nt) acc[nt] = (f32x4){0.f, 0.f, 0.f, 0.f};
            #pragma unroll
            for (int nt = 0; nt < 4; ++nt) {
                acc[nt] = __builtin_amdgcn_mfma_f32_16x16x32_bf16(Ah0.s, bh[nt][0], acc[nt], 0, 0, 0);
                acc[nt] = __builtin_amdgcn_mfma_f32_16x16x32_bf16(Al0.s, bh[nt][0], acc[nt], 0, 0, 0);
                acc[nt] = __builtin_amdgcn_mfma_f32_16x16x32_bf16(Ah1.s, bh[nt][1], acc[nt], 0, 0, 0);
                acc[nt] = __builtin_amdgcn_mfma_f32_16x16x32_bf16(Al1.s, bh[nt][1], acc[nt], 0, 0, 0);
            }
            // stage-2: contract u within wave's tile, then across quads
            #pragma unroll
            for (int nt = 0; nt < 4; ++nt) {
                float ps = acc[nt][0] * wyz[nt][0] + acc[nt][1] * wyz[nt][1]
                         + acc[nt][2] * wyz[nt][2] + acc[nt][3] * wyz[nt][3];
                ps += __shfl_xor(ps, 16, 64);
                ps += __shfl_xor(ps, 32, 64);
                if (q == 0) REDb[k * 256 + w * 64 + nt * 16 + ln] = ps;
            }
        }
        __syncthreads();
        // cross-wave reduce + store: 256 threads, one output each, coalesced per 64
        {
            const int kk = t >> 6, p = t & 63;
            const int c = g4 * 4 + kk;
            const float* Rk = REDb + kk * 256;
            const float o = Rk[p] + Rk[64 + p] + Rk[128 + p] + Rk[192 + p];
            out[(size_t)(cbase + c) * (HH * WW) + i * 64 + p] = o;
        }
    }
}

extern "C" void kernel_launch(void* const* d_in, const int* in_sizes, int n_in,
                              void* d_out, int out_size, void* d_ws, size_t ws_size,
                              hipStream_t stream) {
    const float* inp    = (const float*)d_in[0];
    const float* exPx   = (const float*)d_in[1];
    const float* exPy   = (const float*)d_in[2];
    const float* sigmax = (const float*)d_in[3];
    const float* sigmay = (const float*)d_in[4];
    float* out = (float*)d_out;

    hipLaunchKernelGGL(swap_fused_kernel, dim3(BB * HH * 2), dim3(256), 0, stream,
                       inp, exPx, exPy, sigmax, sigmay, out);
}

// Round 4
// 93.083 us; speedup vs baseline: 2.0426x; 1.0159x over previous
//
#include <hip/hip_runtime.h>

// SwapV2: Gaussian-weighted separable soft gather — fused single-kernel MFMA.
//   t'[u][p] = sum_v X[u][v] * wx[v][p]     (bf16 MFMA, A=X trunc hi/lo split,
//                                            B=wx single RNE bf16 -> 4 MFMA/tile)
//   out[p]   = sum_u wy[u][p] * t'[u][p] * invZ[p]   (fp32 VALU stage-2)
// Block = (b, i, c-half), 256 thr, wave w owns u-tile mt=w.
// R4: (1) single-barrier channel loop — RED[16ch][256] (16 KB) overlays the dead
// WYS region, so all 16 channels stream with no intervening __syncthreads;
// (2) XCD swizzle b = blockIdx&7 -> per-XCD X working set = 2 MB, L2-resident.

#define BB 8
#define CC 32
#define HH 64
#define WW 64

typedef __attribute__((ext_vector_type(8))) short short8;   // 8 bf16 (4 VGPRs)
typedef __attribute__((ext_vector_type(4))) float f32x4;    // 4 fp32 acc
typedef unsigned int uint;

__device__ __forceinline__ uint rn_bf16(float f) {
    uint u = __float_as_uint(f);
    return (u + 0x7FFFu + ((u >> 16) & 1u)) >> 16;   // round-to-nearest-even
}

// truncation split of two fp32 into packed bf16 hi + packed bf16 lo.
// hi = top 16 bits (trunc); lo = x - hi (exact), then trunc. residual <= 2^-16|x|.
__device__ __forceinline__ void split_pair(float f0, float f1, uint& hi, uint& lo) {
    const uint u0 = __float_as_uint(f0), u1 = __float_as_uint(f1);
    hi = (u0 >> 16) | (u1 & 0xFFFF0000u);
    const float l0 = f0 - __uint_as_float(u0 & 0xFFFF0000u);
    const float l1 = f1 - __uint_as_float(u1 & 0xFFFF0000u);
    lo = (__float_as_uint(l0) >> 16) | (__float_as_uint(l1) & 0xFFFF0000u);
}

// ---------------- LDS layout (bytes) ----------------
#define WYS_OFF   0        // WYs[u][65] fp32   : 64*65*4 = 16640  (dead after hoist)
#define WXH_OFF   16640    // WXh[p][72] bf16   : 64*144  = 9216   (dead after hoist)
#define SUM_OFF   25856    // SUMY[256]+SUMX[256] fp32 : 2048     (phase 0 only)
#define INVZ_OFF  27904    // INVZ[64] fp32     : 256
#define LDS_BYTES 28160
#define RED_OFF   0        // RED[16ch][256] fp32 : 16384 — overlays WYS (dead)

__global__ __launch_bounds__(256, 4)
void swap_fused_kernel(const float* __restrict__ inp,
                       const float* __restrict__ exPx, const float* __restrict__ exPy,
                       const float* __restrict__ sigmax, const float* __restrict__ sigmay,
                       float* __restrict__ out)
{
    __shared__ __align__(16) char lds[LDS_BYTES];
    const int t    = threadIdx.x;
    const int lane = t & 63;
    const int w    = t >> 6;          // wave id == u-tile mt
    const int q    = (t >> 4) & 3;    // quad within wave
    const int ln   = t & 15;
    // XCD swizzle: round-robin dispatch maps block n -> XCD n%8, so put batch
    // in the low 3 bits: all 128 blocks of batch b share one XCD -> X[b]
    // (2 MB fp32) is L2-resident for its 64x re-reads. Heuristic only.
    const int bid   = blockIdx.x;     // ((i*2 + chalf) << 3) | b
    const int b     = bid & 7;
    const int r     = bid >> 3;
    const int chalf = r & 1;
    const int i     = r >> 1;
    const int bi    = b * 64 + i;

    float* WYS = (float*)(lds + WYS_OFF);

    // -------- phase 0: per-pixel weights (wy fp32; wx RNE bf16, B-layout) --------
    {
        const int p = lane;           // pixel j of this row
        const int g = w;              // coord group (16 coords)
        const int pixBase = bi * 64 + p;
        const float ey = exPy[pixBase], ex = exPx[pixBase];
        const float isy = 1.0f / sigmay[pixBase], isx = 1.0f / sigmax[pixBase];
        float sy = 0.0f, sx = 0.0f;
        #pragma unroll
        for (int k = 0; k < 16; ++k) {
            const int u = g * 16 + k;
            const float dy = ((float)u - ey) * isy;
            const float wy = __expf(-0.5f * dy * dy);
            WYS[u * 65 + p] = wy;
            sy += wy;
        }
        uint* WXH = (uint*)(lds + WXH_OFF);
        #pragma unroll
        for (int j = 0; j < 8; ++j) {
            const int v0 = g * 16 + 2 * j;
            const float dx0 = ((float)v0       - ex) * isx;
            const float dx1 = ((float)(v0 + 1) - ex) * isx;
            const float wx0 = __expf(-0.5f * dx0 * dx0);
            const float wx1 = __expf(-0.5f * dx1 * dx1);
            sx += wx0 + wx1;
            WXH[p * 36 + g * 8 + j] = rn_bf16(wx0) | (rn_bf16(wx1) << 16);
        }
        float* SUMY = (float*)(lds + SUM_OFF);
        float* SUMX = SUMY + 256;
        SUMY[g * 64 + p] = sy;
        SUMX[g * 64 + p] = sx;
    }
    __syncthreads();
    float* INVZ = (float*)(lds + INVZ_OFF);
    if (t < 64) {
        float* SUMY = (float*)(lds + SUM_OFF);
        float* SUMX = SUMY + 256;
        const float sy = SUMY[t] + SUMY[64 + t] + SUMY[128 + t] + SUMY[192 + t];
        const float sx = SUMX[t] + SUMX[64 + t] + SUMX[128 + t] + SUMX[192 + t];
        INVZ[t] = 1.0f / (sy * sx + 1e-8f);
    }
    __syncthreads();

    // -------- hoist channel-invariant fragments into registers --------
    // B-frag (wx): lane holds B[k = ks*32 + q*8 + j][n = nt*16 + ln]
    short8 bh[4][2];
    #pragma unroll
    for (int nt = 0; nt < 4; ++nt)
        #pragma unroll
        for (int ks = 0; ks < 2; ++ks)
            bh[nt][ks] = *(const short8*)(lds + WXH_OFF + (nt * 16 + ln) * 144 + ks * 64 + q * 16);
    // wy * invZ: lane needs wy[u = w*16 + q*4 + r][p = nt*16 + ln]
    float wyz[4][4];
    #pragma unroll
    for (int nt = 0; nt < 4; ++nt) {
        const float iz = INVZ[nt * 16 + ln];
        #pragma unroll
        for (int rr = 0; rr < 4; ++rr)
            wyz[nt][rr] = WYS[(w * 16 + q * 4 + rr) * 65 + nt * 16 + ln] * iz;
    }
    __syncthreads();   // phase-0 LDS now dead; RED (overlaying WYS) becomes live

    // -------- channel loop: 16 channels, NO intervening barriers --------
    const int cbase = b * CC + chalf * 16;           // absolute (b,c) plane index
    float* RED = (float*)(lds + RED_OFF);
    // lane's A-row: u = w*16 + ln, k-offset v = ks*32 + q*8 + j
    const float* xrow = inp + (size_t)cbase * 4096 + (w * 16 + ln) * 64 + q * 8;

    #pragma unroll 2
    for (int c = 0; c < 16; ++c) {
        const float4* src = (const float4*)(xrow + (size_t)c * 4096);
        const float4 x0 = src[0];   // v = q*8 + 0..3
        const float4 x1 = src[1];   // v = q*8 + 4..7
        const float4 x2 = src[8];   // v = 32 + q*8 + 0..3
        const float4 x3 = src[9];   // v = 32 + q*8 + 4..7

        union { uint u[4]; short8 s; } Ah0, Al0, Ah1, Al1;
        split_pair(x0.x, x0.y, Ah0.u[0], Al0.u[0]);
        split_pair(x0.z, x0.w, Ah0.u[1], Al0.u[1]);
        split_pair(x1.x, x1.y, Ah0.u[2], Al0.u[2]);
        split_pair(x1.z, x1.w, Ah0.u[3], Al0.u[3]);
        split_pair(x2.x, x2.y, Ah1.u[0], Al1.u[0]);
        split_pair(x2.z, x2.w, Ah1.u[1], Al1.u[1]);
        split_pair(x3.x, x3.y, Ah1.u[2], Al1.u[2]);
        split_pair(x3.z, x3.w, Ah1.u[3], Al1.u[3]);

        f32x4 acc[4];
        #pragma unroll
        for (int nt = 0; nt < 4; ++nt) acc[nt] = (f32x4){0.f, 0.f, 0.f, 0.f};
        #pragma unroll
        for (int nt = 0; nt < 4; ++nt) {
            acc[nt] = __builtin_amdgcn_mfma_f32_16x16x32_bf16(Ah0.s, bh[nt][0], acc[nt], 0, 0, 0);
            acc[nt] = __builtin_amdgcn_mfma_f32_16x16x32_bf16(Al0.s, bh[nt][0], acc[nt], 0, 0, 0);
            acc[nt] = __builtin_amdgcn_mfma_f32_16x16x32_bf16(Ah1.s, bh[nt][1], acc[nt], 0, 0, 0);
            acc[nt] = __builtin_amdgcn_mfma_f32_16x16x32_bf16(Al1.s, bh[nt][1], acc[nt], 0, 0, 0);
        }
        // stage-2: contract u within wave's tile, then across quads
        #pragma unroll
        for (int nt = 0; nt < 4; ++nt) {
            float ps = acc[nt][0] * wyz[nt][0] + acc[nt][1] * wyz[nt][1]
                     + acc[nt][2] * wyz[nt][2] + acc[nt][3] * wyz[nt][3];
            ps += __shfl_xor(ps, 16, 64);
            ps += __shfl_xor(ps, 32, 64);
            if (q == 0) RED[c * 256 + w * 64 + nt * 16 + ln] = ps;
        }
    }
    __syncthreads();

    // -------- epilogue: cross-wave reduce + store, 4 channels per thread --------
    {
        const int kk = t >> 6, p = t & 63;
        #pragma unroll
        for (int g = 0; g < 4; ++g) {
            const int c = g * 4 + kk;
            const float* Rk = RED + c * 256;
            const float o = Rk[p] + Rk[64 + p] + Rk[128 + p] + Rk[192 + p];
            out[(size_t)(cbase + c) * (HH * WW) + i * 64 + p] = o;
        }
    }
}

extern "C" void kernel_launch(void* const* d_in, const int* in_sizes, int n_in,
                              void* d_out, int out_size, void* d_ws, size_t ws_size,
                              hipStream_t stream) {
    const float* inp    = (const float*)d_in[0];
    const float* exPx   = (const float*)d_in[1];
    const float* exPy   = (const float*)d_in[2];
    const float* sigmax = (const float*)d_in[3];
    const float* sigmay = (const float*)d_in[4];
    float* out = (float*)d_out;

    hipLaunchKernelGGL(swap_fused_kernel, dim3(BB * HH * 2), dim3(256), 0, stream,
                       inp, exPx, exPy, sigmax, sigmay, out);
}

// Round 5
// 82.251 us; speedup vs baseline: 2.3116x; 1.1317x over previous
//
#include <hip/hip_runtime.h>

// SwapV2: Gaussian-weighted separable soft gather — MFMA + bf16-plane version.
//   t'[u][p] = sum_v X[u][v] * wx[v][p]     (bf16 MFMA, A = X single RNE bf16,
//                                            B = wx single RNE bf16 -> 2 MFMA/nt)
//   out[p]   = sum_u wy[u][p] * t'[u][p] * invZ[p]   (fp32 VALU stage-2)
// R5: (1) preconvert X -> one RNE bf16 plane in d_ws (2 MB): halves re-read
// traffic (268->134 MB) and makes the whole X working set L2-resident on every
// XCD (2 MB < 4 MB) — the R4 kernel was L3-bandwidth bound on fp32 re-reads.
// (2) A-side hi/lo split dropped: 8 MFMA/channel/wave, zero split VALU.
// Block = (b, i, c-half), 256 thr, wave w owns u-tile mt=w; single-barrier
// channel loop with RED[16ch][256] overlaying the dead WYS region.

#define BB 8
#define CC 32
#define HH 64
#define WW 64

typedef __attribute__((ext_vector_type(8))) short short8;   // 8 bf16 (4 VGPRs)
typedef __attribute__((ext_vector_type(4))) float f32x4;    // 4 fp32 acc
typedef unsigned int uint;

__device__ __forceinline__ uint rn_bf16(float f) {
    uint u = __float_as_uint(f);
    return (u + 0x7FFFu + ((u >> 16) & 1u)) >> 16;   // round-to-nearest-even
}

// ---------------- pass 1: fp32 -> single RNE bf16 plane in d_ws ----------------
__global__ void preconvert_kernel(const float* __restrict__ x, uint* __restrict__ hi)
{
    const int n = BB * CC * HH * WW / 2;     // packed bf16-pair count
    int idx = blockIdx.x * blockDim.x + threadIdx.x;
    for (; idx < n; idx += gridDim.x * blockDim.x) {
        const float2 d = ((const float2*)x)[idx];
        hi[idx] = rn_bf16(d.x) | (rn_bf16(d.y) << 16);
    }
}

// ---------------- LDS layout (bytes) ----------------
#define WYS_OFF   0        // WYs[u][65] fp32   : 64*65*4 = 16640  (dead after hoist)
#define WXH_OFF   16640    // WXh[p][72] bf16   : 64*144  = 9216   (dead after hoist)
#define SUM_OFF   25856    // SUMY[256]+SUMX[256] fp32 : 2048     (phase 0 only)
#define INVZ_OFF  27904    // INVZ[64] fp32     : 256
#define LDS_BYTES 28160
#define RED_OFF   0        // RED[16ch][256] fp32 : 16384 — overlays WYS (dead)

__global__ __launch_bounds__(256, 4)
void swap_mfma_kernel(const uint* __restrict__ xhi,
                      const float* __restrict__ exPx, const float* __restrict__ exPy,
                      const float* __restrict__ sigmax, const float* __restrict__ sigmay,
                      float* __restrict__ out)
{
    __shared__ __align__(16) char lds[LDS_BYTES];
    const int t    = threadIdx.x;
    const int lane = t & 63;
    const int w    = t >> 6;          // wave id == u-tile mt
    const int q    = (t >> 4) & 3;    // quad within wave
    const int ln   = t & 15;
    const int bid   = blockIdx.x;     // ((i*2 + chalf) << 3) | b  (XCD heuristic)
    const int b     = bid & 7;
    const int r     = bid >> 3;
    const int chalf = r & 1;
    const int i     = r >> 1;
    const int bi    = b * 64 + i;

    float* WYS = (float*)(lds + WYS_OFF);

    // -------- phase 0: per-pixel weights (wy fp32; wx RNE bf16, B-layout) --------
    {
        const int p = lane;           // pixel j of this row
        const int g = w;              // coord group (16 coords)
        const int pixBase = bi * 64 + p;
        const float ey = exPy[pixBase], ex = exPx[pixBase];
        const float isy = 1.0f / sigmay[pixBase], isx = 1.0f / sigmax[pixBase];
        float sy = 0.0f, sx = 0.0f;
        #pragma unroll
        for (int k = 0; k < 16; ++k) {
            const int u = g * 16 + k;
            const float dy = ((float)u - ey) * isy;
            const float wy = __expf(-0.5f * dy * dy);
            WYS[u * 65 + p] = wy;
            sy += wy;
        }
        uint* WXH = (uint*)(lds + WXH_OFF);
        #pragma unroll
        for (int j = 0; j < 8; ++j) {
            const int v0 = g * 16 + 2 * j;
            const float dx0 = ((float)v0       - ex) * isx;
            const float dx1 = ((float)(v0 + 1) - ex) * isx;
            const float wx0 = __expf(-0.5f * dx0 * dx0);
            const float wx1 = __expf(-0.5f * dx1 * dx1);
            sx += wx0 + wx1;
            WXH[p * 36 + g * 8 + j] = rn_bf16(wx0) | (rn_bf16(wx1) << 16);
        }
        float* SUMY = (float*)(lds + SUM_OFF);
        float* SUMX = SUMY + 256;
        SUMY[g * 64 + p] = sy;
        SUMX[g * 64 + p] = sx;
    }
    __syncthreads();
    float* INVZ = (float*)(lds + INVZ_OFF);
    if (t < 64) {
        float* SUMY = (float*)(lds + SUM_OFF);
        float* SUMX = SUMY + 256;
        const float sy = SUMY[t] + SUMY[64 + t] + SUMY[128 + t] + SUMY[192 + t];
        const float sx = SUMX[t] + SUMX[64 + t] + SUMX[128 + t] + SUMX[192 + t];
        INVZ[t] = 1.0f / (sy * sx + 1e-8f);
    }
    __syncthreads();

    // -------- hoist channel-invariant fragments into registers --------
    // B-frag (wx): lane holds B[k = ks*32 + q*8 + j][n = nt*16 + ln]
    short8 bh[4][2];
    #pragma unroll
    for (int nt = 0; nt < 4; ++nt)
        #pragma unroll
        for (int ks = 0; ks < 2; ++ks)
            bh[nt][ks] = *(const short8*)(lds + WXH_OFF + (nt * 16 + ln) * 144 + ks * 64 + q * 16);
    // wy * invZ: lane needs wy[u = w*16 + q*4 + r][p = nt*16 + ln]
    float wyz[4][4];
    #pragma unroll
    for (int nt = 0; nt < 4; ++nt) {
        const float iz = INVZ[nt * 16 + ln];
        #pragma unroll
        for (int rr = 0; rr < 4; ++rr)
            wyz[nt][rr] = WYS[(w * 16 + q * 4 + rr) * 65 + nt * 16 + ln] * iz;
    }
    __syncthreads();   // phase-0 LDS now dead; RED (overlaying WYS) becomes live

    // -------- channel loop: 16 channels, NO intervening barriers --------
    const int cbase = b * CC + chalf * 16;           // absolute (b,c) plane index
    float* RED = (float*)(lds + RED_OFF);
    // lane's A-row in the bf16 plane: u = w*16 + ln, v = ks*32 + q*8 + j
    const uint* xrow = xhi + (size_t)cbase * 2048 + (w * 16 + ln) * 32 + q * 4;

    #pragma unroll 4
    for (int c = 0; c < 16; ++c) {
        const uint4* src = (const uint4*)(xrow + (size_t)c * 2048);
        union { uint4 v; short8 s; } A0, A1;
        A0.v = src[0];   // v = q*8 + 0..7        (8 bf16, 16 B)
        A1.v = src[4];   // v = 32 + q*8 + 0..7

        f32x4 acc[4];
        #pragma unroll
        for (int nt = 0; nt < 4; ++nt) acc[nt] = (f32x4){0.f, 0.f, 0.f, 0.f};
        #pragma unroll
        for (int nt = 0; nt < 4; ++nt) {
            acc[nt] = __builtin_amdgcn_mfma_f32_16x16x32_bf16(A0.s, bh[nt][0], acc[nt], 0, 0, 0);
            acc[nt] = __builtin_amdgcn_mfma_f32_16x16x32_bf16(A1.s, bh[nt][1], acc[nt], 0, 0, 0);
        }
        // stage-2: contract u within wave's tile, then across quads
        #pragma unroll
        for (int nt = 0; nt < 4; ++nt) {
            float ps = acc[nt][0] * wyz[nt][0] + acc[nt][1] * wyz[nt][1]
                     + acc[nt][2] * wyz[nt][2] + acc[nt][3] * wyz[nt][3];
            ps += __shfl_xor(ps, 16, 64);
            ps += __shfl_xor(ps, 32, 64);
            if (q == 0) RED[c * 256 + w * 64 + nt * 16 + ln] = ps;
        }
    }
    __syncthreads();

    // -------- epilogue: cross-wave reduce + store, 4 channels per thread --------
    {
        const int kk = t >> 6, p = t & 63;
        #pragma unroll
        for (int g = 0; g < 4; ++g) {
            const int c = g * 4 + kk;
            const float* Rk = RED + c * 256;
            const float o = Rk[p] + Rk[64 + p] + Rk[128 + p] + Rk[192 + p];
            out[(size_t)(cbase + c) * (HH * WW) + i * 64 + p] = o;
        }
    }
}

// ---------------- fallback (R4 proven fused kernel, fp32 loads + A split) ----------------
__device__ __forceinline__ void split_pair(float f0, float f1, uint& hi, uint& lo) {
    const uint u0 = __float_as_uint(f0), u1 = __float_as_uint(f1);
    hi = (u0 >> 16) | (u1 & 0xFFFF0000u);
    const float l0 = f0 - __uint_as_float(u0 & 0xFFFF0000u);
    const float l1 = f1 - __uint_as_float(u1 & 0xFFFF0000u);
    lo = (__float_as_uint(l0) >> 16) | (__float_as_uint(l1) & 0xFFFF0000u);
}

__global__ __launch_bounds__(256, 4)
void swap_fused_kernel(const float* __restrict__ inp,
                       const float* __restrict__ exPx, const float* __restrict__ exPy,
                       const float* __restrict__ sigmax, const float* __restrict__ sigmay,
                       float* __restrict__ out)
{
    __shared__ __align__(16) char lds[LDS_BYTES];
    const int t = threadIdx.x;
    const int lane = t & 63, w = t >> 6, q = (t >> 4) & 3, ln = t & 15;
    const int bid = blockIdx.x;
    const int b = bid & 7, r = bid >> 3;
    const int chalf = r & 1, i = r >> 1;
    const int bi = b * 64 + i;

    float* WYS = (float*)(lds + WYS_OFF);
    {
        const int p = lane, g = w;
        const int pixBase = bi * 64 + p;
        const float ey = exPy[pixBase], ex = exPx[pixBase];
        const float isy = 1.0f / sigmay[pixBase], isx = 1.0f / sigmax[pixBase];
        float sy = 0.0f, sx = 0.0f;
        #pragma unroll
        for (int k = 0; k < 16; ++k) {
            const int u = g * 16 + k;
            const float dy = ((float)u - ey) * isy;
            const float wy = __expf(-0.5f * dy * dy);
            WYS[u * 65 + p] = wy; sy += wy;
        }
        uint* WXH = (uint*)(lds + WXH_OFF);
        #pragma unroll
        for (int j = 0; j < 8; ++j) {
            const int v0 = g * 16 + 2 * j;
            const float dx0 = ((float)v0 - ex) * isx;
            const float dx1 = ((float)(v0 + 1) - ex) * isx;
            const float wx0 = __expf(-0.5f * dx0 * dx0);
            const float wx1 = __expf(-0.5f * dx1 * dx1);
            sx += wx0 + wx1;
            WXH[p * 36 + g * 8 + j] = rn_bf16(wx0) | (rn_bf16(wx1) << 16);
        }
        float* SUMY = (float*)(lds + SUM_OFF);
        float* SUMX = SUMY + 256;
        SUMY[g * 64 + p] = sy; SUMX[g * 64 + p] = sx;
    }
    __syncthreads();
    float* INVZ = (float*)(lds + INVZ_OFF);
    if (t < 64) {
        float* SUMY = (float*)(lds + SUM_OFF);
        float* SUMX = SUMY + 256;
        const float sy = SUMY[t] + SUMY[64 + t] + SUMY[128 + t] + SUMY[192 + t];
        const float sx = SUMX[t] + SUMX[64 + t] + SUMX[128 + t] + SUMX[192 + t];
        INVZ[t] = 1.0f / (sy * sx + 1e-8f);
    }
    __syncthreads();
    short8 bh[4][2];
    #pragma unroll
    for (int nt = 0; nt < 4; ++nt)
        #pragma unroll
        for (int ks = 0; ks < 2; ++ks)
            bh[nt][ks] = *(const short8*)(lds + WXH_OFF + (nt * 16 + ln) * 144 + ks * 64 + q * 16);
    float wyz[4][4];
    #pragma unroll
    for (int nt = 0; nt < 4; ++nt) {
        const float iz = INVZ[nt * 16 + ln];
        #pragma unroll
        for (int rr = 0; rr < 4; ++rr)
            wyz[nt][rr] = WYS[(w * 16 + q * 4 + rr) * 65 + nt * 16 + ln] * iz;
    }
    __syncthreads();
    const int cbase = b * CC + chalf * 16;
    float* RED = (float*)(lds + RED_OFF);
    const float* xrow = inp + (size_t)cbase * 4096 + (w * 16 + ln) * 64 + q * 8;
    #pragma unroll 2
    for (int c = 0; c < 16; ++c) {
        const float4* src = (const float4*)(xrow + (size_t)c * 4096);
        const float4 x0 = src[0], x1 = src[1], x2 = src[8], x3 = src[9];
        union { uint u[4]; short8 s; } Ah0, Al0, Ah1, Al1;
        split_pair(x0.x, x0.y, Ah0.u[0], Al0.u[0]);
        split_pair(x0.z, x0.w, Ah0.u[1], Al0.u[1]);
        split_pair(x1.x, x1.y, Ah0.u[2], Al0.u[2]);
        split_pair(x1.z, x1.w, Ah0.u[3], Al0.u[3]);
        split_pair(x2.x, x2.y, Ah1.u[0], Al1.u[0]);
        split_pair(x2.z, x2.w, Ah1.u[1], Al1.u[1]);
        split_pair(x3.x, x3.y, Ah1.u[2], Al1.u[2]);
        split_pair(x3.z, x3.w, Ah1.u[3], Al1.u[3]);
        f32x4 acc[4];
        #pragma unroll
        for (int nt = 0; nt < 4; ++nt) acc[nt] = (f32x4){0.f, 0.f, 0.f, 0.f};
        #pragma unroll
        for (int nt = 0; nt < 4; ++nt) {
            acc[nt] = __builtin_amdgcn_mfma_f32_16x16x32_bf16(Ah0.s, bh[nt][0], acc[nt], 0, 0, 0);
            acc[nt] = __builtin_amdgcn_mfma_f32_16x16x32_bf16(Al0.s, bh[nt][0], acc[nt], 0, 0, 0);
            acc[nt] = __builtin_amdgcn_mfma_f32_16x16x32_bf16(Ah1.s, bh[nt][1], acc[nt], 0, 0, 0);
            acc[nt] = __builtin_amdgcn_mfma_f32_16x16x32_bf16(Al1.s, bh[nt][1], acc[nt], 0, 0, 0);
        }
        #pragma unroll
        for (int nt = 0; nt < 4; ++nt) {
            float ps = acc[nt][0] * wyz[nt][0] + acc[nt][1] * wyz[nt][1]
                     + acc[nt][2] * wyz[nt][2] + acc[nt][3] * wyz[nt][3];
            ps += __shfl_xor(ps, 16, 64);
            ps += __shfl_xor(ps, 32, 64);
            if (q == 0) RED[c * 256 + w * 64 + nt * 16 + ln] = ps;
        }
    }
    __syncthreads();
    {
        const int kk = t >> 6, p = t & 63;
        #pragma unroll
        for (int g = 0; g < 4; ++g) {
            const int c = g * 4 + kk;
            const float* Rk = RED + c * 256;
            const float o = Rk[p] + Rk[64 + p] + Rk[128 + p] + Rk[192 + p];
            out[(size_t)(cbase + c) * (HH * WW) + i * 64 + p] = o;
        }
    }
}

extern "C" void kernel_launch(void* const* d_in, const int* in_sizes, int n_in,
                              void* d_out, int out_size, void* d_ws, size_t ws_size,
                              hipStream_t stream) {
    const float* inp    = (const float*)d_in[0];
    const float* exPx   = (const float*)d_in[1];
    const float* exPy   = (const float*)d_in[2];
    const float* sigmax = (const float*)d_in[3];
    const float* sigmay = (const float*)d_in[4];
    float* out = (float*)d_out;

    const size_t plane_bytes = (size_t)BB * CC * HH * WW * 2;   // 2 MB bf16 plane
    if (ws_size >= plane_bytes) {
        uint* xhi = (uint*)d_ws;
        hipLaunchKernelGGL(preconvert_kernel, dim3(1024), dim3(256), 0, stream, inp, xhi);
        hipLaunchKernelGGL(swap_mfma_kernel, dim3(BB * HH * 2), dim3(256), 0, stream,
                           xhi, exPx, exPy, sigmax, sigmay, out);
    } else {
        hipLaunchKernelGGL(swap_fused_kernel, dim3(BB * HH * 2), dim3(256), 0, stream,
                           inp, exPx, exPy, sigmax, sigmay, out);
    }
}